// Round 1
// baseline (163.079 us; speedup 1.0000x reference)
//
#include <hip/hip_runtime.h>
#include <math.h>

#define NLIB 128
#define DZ   1024

static __device__ __forceinline__ int iclamp(int v, int lo, int hi) {
    return v < lo ? lo : (v > hi ? hi : v);
}

// ---------------------------------------------------------------------------
// Kernel A: image-level kNN. dist2[n] = ||z_lib[n]-z||^2, select k smallest,
// write z_score = mean(sqrt(dist2_selected)) and the selected index list.
// Single block, 1024 threads = 16 waves, each wave reduces 8 rows.
// ---------------------------------------------------------------------------
__global__ __launch_bounds__(1024)
void knn_select_kernel(const float* __restrict__ z, const float* __restrict__ z_lib,
                       const int* __restrict__ kp, float* __restrict__ zscore_out,
                       int* __restrict__ idx_out) {
    __shared__ float dist2[NLIB];
    __shared__ float contrib[NLIB];
    __shared__ int cnt;
    const int tid  = threadIdx.x;
    const int wave = tid >> 6, lane = tid & 63;

    for (int r = 0; r < 8; ++r) {               // 16 waves * 8 rows = 128
        const int n = wave * 8 + r;
        const float* row = z_lib + (size_t)n * DZ;
        float acc = 0.f;
#pragma unroll
        for (int i = 0; i < DZ / 64; ++i) {
            float d = row[lane + i * 64] - z[lane + i * 64];
            acc += d * d;
        }
        for (int off = 32; off > 0; off >>= 1) acc += __shfl_down(acc, off, 64);
        if (lane == 0) dist2[n] = acc;
    }
    if (tid == 0) cnt = 0;
    __syncthreads();

    const int k = *kp;
    if (tid < NLIB) {
        const float d = dist2[tid];
        int rank = 0;
        for (int m = 0; m < NLIB; ++m) {
            const float dm = dist2[m];
            rank += (dm < d || (dm == d && m < tid)) ? 1 : 0;
        }
        const bool sel = (rank < k);
        contrib[tid] = sel ? sqrtf(d) : 0.f;
        if (sel) {
            int p = atomicAdd(&cnt, 1);
            idx_out[p] = tid;
        }
    }
    __syncthreads();
    if (tid == 0) {
        float s = 0.f;
        for (int m = 0; m < NLIB; ++m) s += contrib[m];   // fixed order: deterministic
        zscore_out[0] = s / (float)k;
    }
}

// ---------------------------------------------------------------------------
// Kernel B: per-level partial squared distances.
// grid = (pixel-quad blocks, channel-chunks, n-slot<=128). Each thread owns 4
// consecutive pixels (float4 loads, coalesced) and sums (lib-fmap)^2 over its
// channel chunk. Output slot d2[cc][n][quad] -> no atomics, deterministic.
// ---------------------------------------------------------------------------
template <int C, int HW, int CCH, int BLK>
__global__ void level_dist_kernel(const float* __restrict__ lib, const float* __restrict__ fmap,
                                  const int* __restrict__ kp, const int* __restrict__ idx,
                                  float4* __restrict__ d2) {
    const int n = blockIdx.z;
    if (n >= *kp) return;
    constexpr int NQ = HW / 4;
    const int q = blockIdx.x * BLK + threadIdx.x;
    if (q >= NQ) return;
    const int cc = blockIdx.y;
    constexpr int CL = C / CCH;
    const int img = idx[n];
    const float4* __restrict__ lp =
        (const float4*)(lib + (size_t)img * C * HW + (size_t)cc * CL * HW) + q;
    const float4* __restrict__ fp = (const float4*)(fmap + (size_t)cc * CL * HW) + q;
    float4 acc = make_float4(0.f, 0.f, 0.f, 0.f);
#pragma unroll 8
    for (int c = 0; c < CL; ++c) {
        float4 a = lp[(size_t)c * NQ];
        float4 b = fp[(size_t)c * NQ];
        float dx = a.x - b.x, dy = a.y - b.y, dz = a.z - b.z, dw = a.w - b.w;
        acc.x += dx * dx; acc.y += dy * dy; acc.z += dz * dz; acc.w += dw * dw;
    }
    d2[((size_t)cc * NLIB + n) * NQ + q] = acc;
}

// ---------------------------------------------------------------------------
// Kernel C: smin[pix] = sqrt( min_{n<k} sum_cc d2[cc][n][pix] )
// ---------------------------------------------------------------------------
template <int HW, int CCH>
__global__ void level_min_kernel(const float4* __restrict__ d2, const int* __restrict__ kp,
                                 float* __restrict__ smin) {
    constexpr int NQ = HW / 4;
    const int q = blockIdx.x * blockDim.x + threadIdx.x;
    if (q >= NQ) return;
    const int k = *kp;
    float4 mn = make_float4(3.4e38f, 3.4e38f, 3.4e38f, 3.4e38f);
#pragma unroll 2
    for (int n = 0; n < k; ++n) {
        float4 s = make_float4(0.f, 0.f, 0.f, 0.f);
#pragma unroll
        for (int cc = 0; cc < CCH; ++cc) {
            float4 v = d2[((size_t)cc * NLIB + n) * NQ + q];
            s.x += v.x; s.y += v.y; s.z += v.z; s.w += v.w;
        }
        mn.x = fminf(mn.x, s.x); mn.y = fminf(mn.y, s.y);
        mn.z = fminf(mn.z, s.z); mn.w = fminf(mn.w, s.w);
    }
    smin[q * 4 + 0] = sqrtf(mn.x);
    smin[q * 4 + 1] = sqrtf(mn.y);
    smin[q * 4 + 2] = sqrtf(mn.z);
    smin[q * 4 + 3] = sqrtf(mn.w);
}

// ---------------------------------------------------------------------------
// Kernel D: bilinear upsample (half-pixel centers, edge clamp) of the three
// per-level maps to 224x224 and sum.
// ---------------------------------------------------------------------------
static __device__ __forceinline__ void samp(int o, float inv_f, int sz, int& i0, int& i1, float& fr) {
    float c  = (o + 0.5f) * inv_f - 0.5f;   // inv_f is a power of two: exact
    float fl = floorf(c);
    fr = c - fl;
    int i = (int)fl;
    i0 = iclamp(i, 0, sz - 1);
    i1 = iclamp(i + 1, 0, sz - 1);
}

static __device__ __forceinline__ float bilerp(const float* __restrict__ s, int w,
                                               int y0, int y1, int x0, int x1,
                                               float fy, float fx) {
    float a = s[y0 * w + x0], b = s[y0 * w + x1];
    float c = s[y1 * w + x0], d = s[y1 * w + x1];
    float top = a + (b - a) * fx;
    float bot = c + (d - c) * fx;
    return top + (bot - top) * fy;
}

__global__ void upsample_sum_kernel(const float* __restrict__ s0, const float* __restrict__ s1,
                                    const float* __restrict__ s2, float* __restrict__ smap) {
    const int i = blockIdx.x * blockDim.x + threadIdx.x;
    if (i >= 224 * 224) return;
    const int y = i / 224, x = i % 224;
    int y0, y1, x0, x1; float fy, fx;
    float v = 0.f;
    samp(y, 0.25f, 56, y0, y1, fy);  samp(x, 0.25f, 56, x0, x1, fx);
    v += bilerp(s0, 56, y0, y1, x0, x1, fy, fx);
    samp(y, 0.125f, 28, y0, y1, fy); samp(x, 0.125f, 28, x0, x1, fx);
    v += bilerp(s1, 28, y0, y1, x0, x1, fy, fx);
    samp(y, 0.0625f, 14, y0, y1, fy); samp(x, 0.0625f, 14, x0, x1, fx);
    v += bilerp(s2, 14, y0, y1, x0, x1, fy, fx);
    smap[i] = v;
}

// ---------------------------------------------------------------------------
// Kernel E/F: separable 17-tap Gaussian blur, sigma=4, reflect padding
// (numpy 'reflect': no edge repeat). Weights computed per-thread (cheap).
// ---------------------------------------------------------------------------
static __device__ __forceinline__ int reflect224(int i) {
    if (i < 0) i = -i;
    if (i > 223) i = 446 - i;
    return i;
}

static __device__ __forceinline__ void gauss_w(float* w) {
    float tot = 0.f;
#pragma unroll
    for (int j = 0; j < 17; ++j) {
        float t = (j - 8) * 0.25f;           // (x / sigma), sigma = 4
        w[j] = expf(-0.5f * t * t);
        tot += w[j];
    }
    float inv = 1.f / tot;
#pragma unroll
    for (int j = 0; j < 17; ++j) w[j] *= inv;
}

__global__ void blur_h_kernel(const float* __restrict__ in, float* __restrict__ out) {
    const int i = blockIdx.x * blockDim.x + threadIdx.x;
    if (i >= 224 * 224) return;
    const int y = i / 224, x = i % 224;
    float w[17];
    gauss_w(w);
    float acc = 0.f;
#pragma unroll
    for (int j = 0; j < 17; ++j) acc += w[j] * in[y * 224 + reflect224(x + j - 8)];
    out[i] = acc;
}

__global__ void blur_v_kernel(const float* __restrict__ in, float* __restrict__ out) {
    const int i = blockIdx.x * blockDim.x + threadIdx.x;
    if (i >= 224 * 224) return;
    const int y = i / 224, x = i % 224;
    float w[17];
    gauss_w(w);
    float acc = 0.f;
#pragma unroll
    for (int j = 0; j < 17; ++j) acc += w[j] * in[reflect224(y + j - 8) * 224 + x];
    out[i] = acc;
}

// ---------------------------------------------------------------------------
// Launch
// ---------------------------------------------------------------------------
extern "C" void kernel_launch(void* const* d_in, const int* in_sizes, int n_in,
                              void* d_out, int out_size, void* d_ws, size_t ws_size,
                              hipStream_t stream) {
    const float* z     = (const float*)d_in[0];
    const float* z_lib = (const float*)d_in[1];
    const float* fmap0 = (const float*)d_in[2];
    const float* fmap1 = (const float*)d_in[3];
    const float* fmap2 = (const float*)d_in[4];
    const float* lib0  = (const float*)d_in[5];
    const float* lib1  = (const float*)d_in[6];
    const float* lib2  = (const float*)d_in[7];
    const int*   kp    = (const int*)d_in[8];
    float* out = (float*)d_out;

    // workspace layout (all 16B aligned)
    constexpr size_t OFF_IDX   = 0;
    constexpr size_t OFF_D2_0  = 512;                                   // 128 ints
    constexpr size_t SZ_D2_0   = (size_t)2  * NLIB * (3136 / 4) * 16;   // CCH0=2
    constexpr size_t OFF_D2_1  = OFF_D2_0 + SZ_D2_0;
    constexpr size_t SZ_D2_1   = (size_t)4  * NLIB * (784 / 4) * 16;    // CCH1=4
    constexpr size_t OFF_D2_2  = OFF_D2_1 + SZ_D2_1;
    constexpr size_t SZ_D2_2   = (size_t)16 * NLIB * (196 / 4) * 16;    // CCH2=16
    constexpr size_t OFF_SMIN0 = OFF_D2_2 + SZ_D2_2;
    constexpr size_t OFF_SMIN1 = OFF_SMIN0 + 3136 * 4;
    constexpr size_t OFF_SMIN2 = OFF_SMIN1 + 784 * 4;
    constexpr size_t OFF_SMAP  = OFF_SMIN2 + 196 * 4 + 12;              // keep 16B align
    constexpr size_t OFF_TMP   = OFF_SMAP + (size_t)50176 * 4;

    char* ws = (char*)d_ws;
    int*    idx   = (int*)(ws + OFF_IDX);
    float4* d2_0  = (float4*)(ws + OFF_D2_0);
    float4* d2_1  = (float4*)(ws + OFF_D2_1);
    float4* d2_2  = (float4*)(ws + OFF_D2_2);
    float*  smin0 = (float*)(ws + OFF_SMIN0);
    float*  smin1 = (float*)(ws + OFF_SMIN1);
    float*  smin2 = (float*)(ws + OFF_SMIN2);
    float*  smap  = (float*)(ws + OFF_SMAP);
    float*  tmp   = (float*)(ws + OFF_TMP);

    // 1) kNN select + z_score
    knn_select_kernel<<<dim3(1), dim3(1024), 0, stream>>>(z, z_lib, kp, out, idx);

    // 2) per-level distances over selected images (n-slot grid sized for max k=128)
    level_dist_kernel<256, 3136, 2, 256><<<dim3(4, 2, 128), dim3(256), 0, stream>>>(lib0, fmap0, kp, idx, d2_0);
    level_dist_kernel<512, 784, 4, 64><<<dim3(4, 4, 128), dim3(64), 0, stream>>>(lib1, fmap1, kp, idx, d2_1);
    level_dist_kernel<1024, 196, 16, 64><<<dim3(1, 16, 128), dim3(64), 0, stream>>>(lib2, fmap2, kp, idx, d2_2);

    // 3) min over k, sqrt
    level_min_kernel<3136, 2><<<dim3(4), dim3(256), 0, stream>>>(d2_0, kp, smin0);
    level_min_kernel<784, 4><<<dim3(4), dim3(64), 0, stream>>>(d2_1, kp, smin1);
    level_min_kernel<196, 16><<<dim3(1), dim3(64), 0, stream>>>(d2_2, kp, smin2);

    // 4) bilinear upsample + sum (224*224 = 196*256)
    upsample_sum_kernel<<<dim3(196), dim3(256), 0, stream>>>(smin0, smin1, smin2, smap);

    // 5) separable gaussian blur -> d_out[1:]
    blur_h_kernel<<<dim3(196), dim3(256), 0, stream>>>(smap, tmp);
    blur_v_kernel<<<dim3(196), dim3(256), 0, stream>>>(tmp, out + 1);
}

// Round 2
// 119.087 us; speedup vs baseline: 1.3694x; 1.3694x over previous
//
#include <hip/hip_runtime.h>
#include <math.h>

#define NLIB 128
#define INFBITS 0x7F800000u

static __device__ __forceinline__ int iclamp(int v, int lo, int hi) {
    return v < lo ? lo : (v > hi ? hi : v);
}

// ---------------------------------------------------------------------------
// Kernel 1: per-row squared distance ||z_lib[n]-z||^2. 128 blocks x 256 thr.
// ---------------------------------------------------------------------------
__global__ __launch_bounds__(256)
void row_dist_kernel(const float* __restrict__ z, const float* __restrict__ z_lib,
                     float* __restrict__ dist2) {
    const int n = blockIdx.x;
    const int tid = threadIdx.x, wave = tid >> 6, lane = tid & 63;
    const float4 a = ((const float4*)(z_lib + (size_t)n * 1024))[tid];
    const float4 b = ((const float4*)z)[tid];
    float dx = a.x - b.x, dy = a.y - b.y, dz = a.z - b.z, dw = a.w - b.w;
    float acc = dx * dx + dy * dy + dz * dz + dw * dw;
    for (int off = 32; off > 0; off >>= 1) acc += __shfl_down(acc, off, 64);
    __shared__ float ws4[4];
    if (lane == 0) ws4[wave] = acc;
    __syncthreads();
    if (tid == 0) dist2[n] = ws4[0] + ws4[1] + ws4[2] + ws4[3];
}

// ---------------------------------------------------------------------------
// Kernel 2: rank-select k smallest, write z_score + idx[rank]=n (no atomics,
// deterministic). Also initializes the three smin-bits buffers to +inf.
// ---------------------------------------------------------------------------
__global__ __launch_bounds__(128)
void select_kernel(const float* __restrict__ dist2, const int* __restrict__ kp,
                   float* __restrict__ zscore, int* __restrict__ idx,
                   unsigned* __restrict__ sb0, unsigned* __restrict__ sb1,
                   unsigned* __restrict__ sb2) {
    __shared__ float d[NLIB];
    __shared__ float contrib[NLIB];
    const int tid = threadIdx.x;
    d[tid] = dist2[tid];
    for (int i = tid; i < 3136; i += 128) sb0[i] = INFBITS;
    for (int i = tid; i < 784;  i += 128) sb1[i] = INFBITS;
    for (int i = tid; i < 196;  i += 128) sb2[i] = INFBITS;
    __syncthreads();
    const int k = *kp;
    const float dd = d[tid];
    int rank = 0;
#pragma unroll 8
    for (int m = 0; m < NLIB; ++m) {
        const float dm = d[m];
        rank += (dm < dd || (dm == dd && m < tid)) ? 1 : 0;
    }
    const bool sel = (rank < k);
    if (sel) idx[rank] = tid;
    contrib[tid] = sel ? sqrtf(dd) : 0.f;
    __syncthreads();
    if (tid == 0) {
        float s = 0.f;
        for (int m = 0; m < NLIB; ++m) s += contrib[m];   // fixed order
        zscore[0] = s / (float)k;
    }
}

// ---------------------------------------------------------------------------
// Kernel 3: fused per-level partial squared distances (all 3 levels, one
// launch). grid = (25+13+13, 128). Flattened (cc,q) -> uniform 256-thr blocks.
// d2_l[cc][n][quad] float4, no atomics.
// ---------------------------------------------------------------------------
template <int C, int NQ, int CCH>
static __device__ __forceinline__ void dist_level(const float* __restrict__ lib,
                                                  const float* __restrict__ fmap,
                                                  const int* __restrict__ idx, int n, int w,
                                                  float4* __restrict__ d2) {
    constexpr int CL = C / CCH;
    if (w >= CCH * NQ) return;
    const int cc = w / NQ;
    const int q  = w - cc * NQ;
    const int img = idx[n];
    const float4* __restrict__ lp = (const float4*)lib + ((size_t)img * C + cc * CL) * NQ + q;
    const float4* __restrict__ fp = (const float4*)fmap + (size_t)(cc * CL) * NQ + q;
    float4 acc = make_float4(0.f, 0.f, 0.f, 0.f);
#pragma unroll 8
    for (int c = 0; c < CL; ++c) {
        float4 a = lp[(size_t)c * NQ];
        float4 b = fp[(size_t)c * NQ];
        float dx = a.x - b.x, dy = a.y - b.y, dz = a.z - b.z, dw = a.w - b.w;
        acc.x += dx * dx; acc.y += dy * dy; acc.z += dz * dz; acc.w += dw * dw;
    }
    d2[((size_t)cc * NLIB + n) * NQ + q] = acc;
}

__global__ __launch_bounds__(256)
void dist_all_kernel(const float* __restrict__ lib0, const float* __restrict__ fmap0,
                     const float* __restrict__ lib1, const float* __restrict__ fmap1,
                     const float* __restrict__ lib2, const float* __restrict__ fmap2,
                     const int* __restrict__ kp, const int* __restrict__ idx,
                     float4* __restrict__ d2_0, float4* __restrict__ d2_1,
                     float4* __restrict__ d2_2) {
    const int n = blockIdx.y;
    if (n >= *kp) return;
    const int bx = blockIdx.x;
    if (bx < 25) {
        dist_level<256, 784, 8>(lib0, fmap0, idx, n, bx * 256 + threadIdx.x, d2_0);
    } else if (bx < 38) {
        dist_level<512, 196, 16>(lib1, fmap1, idx, n, (bx - 25) * 256 + threadIdx.x, d2_1);
    } else {
        dist_level<1024, 49, 64>(lib2, fmap2, idx, n, (bx - 38) * 256 + threadIdx.x, d2_2);
    }
}

// ---------------------------------------------------------------------------
// Kernel 4: min over k via atomicMin on uint bits (d2 >= 0 -> monotone).
// grid = (5, 16): pixels flattened across levels x 16 n-chunks of 8.
// ---------------------------------------------------------------------------
template <int NQ, int CCH>
static __device__ __forceinline__ void min_level(const float4* __restrict__ d2, int q,
                                                 int n0, int n1, unsigned* __restrict__ sb) {
    float mnx = 3.4e38f, mny = 3.4e38f, mnz = 3.4e38f, mnw = 3.4e38f;
    for (int n = n0; n < n1; ++n) {
        float sx = 0.f, sy = 0.f, sz = 0.f, sw = 0.f;
#pragma unroll 8
        for (int cc = 0; cc < CCH; ++cc) {
            float4 v = d2[((size_t)cc * NLIB + n) * NQ + q];
            sx += v.x; sy += v.y; sz += v.z; sw += v.w;
        }
        mnx = fminf(mnx, sx); mny = fminf(mny, sy);
        mnz = fminf(mnz, sz); mnw = fminf(mnw, sw);
    }
    atomicMin(sb + q * 4 + 0, __float_as_uint(mnx));
    atomicMin(sb + q * 4 + 1, __float_as_uint(mny));
    atomicMin(sb + q * 4 + 2, __float_as_uint(mnz));
    atomicMin(sb + q * 4 + 3, __float_as_uint(mnw));
}

__global__ __launch_bounds__(256)
void min_all_kernel(const float4* __restrict__ d2_0, const float4* __restrict__ d2_1,
                    const float4* __restrict__ d2_2, const int* __restrict__ kp,
                    unsigned* __restrict__ sb0, unsigned* __restrict__ sb1,
                    unsigned* __restrict__ sb2) {
    const int k = *kp;
    const int n0 = blockIdx.y * 8;
    if (n0 >= k) return;
    const int n1 = min(n0 + 8, k);
    const int t = blockIdx.x * 256 + threadIdx.x;
    if (t < 784)       min_level<784, 8>(d2_0, t, n0, n1, sb0);
    else if (t < 980)  min_level<196, 16>(d2_1, t - 784, n0, n1, sb1);
    else if (t < 1029) min_level<49, 64>(d2_2, t - 980, n0, n1, sb2);
}

// ---------------------------------------------------------------------------
// Kernel 5: bilinear upsample (half-pixel, edge clamp) of sqrt(smin-bits),
// summed across levels, fused with horizontal 17-tap gaussian blur (reflect).
// One block per output row.
// ---------------------------------------------------------------------------
static __device__ __forceinline__ void samp(int o, float inv_f, int sz, int& i0, int& i1,
                                            float& fr) {
    float c  = (o + 0.5f) * inv_f - 0.5f;   // inv_f power of two: exact
    float fl = floorf(c);
    fr = c - fl;
    int i = (int)fl;
    i0 = iclamp(i, 0, sz - 1);
    i1 = iclamp(i + 1, 0, sz - 1);
}

static __device__ __forceinline__ float ldsq(const unsigned* __restrict__ sb, int w, int y, int x) {
    return sqrtf(__uint_as_float(sb[y * w + x]));
}

static __device__ __forceinline__ float bilerp_sq(const unsigned* __restrict__ sb, int w,
                                                  int y0, int y1, int x0, int x1,
                                                  float fy, float fx) {
    float a = ldsq(sb, w, y0, x0), b = ldsq(sb, w, y0, x1);
    float c = ldsq(sb, w, y1, x0), d = ldsq(sb, w, y1, x1);
    float top = a + (b - a) * fx;
    float bot = c + (d - c) * fx;
    return top + (bot - top) * fy;
}

static __device__ __forceinline__ int reflect224(int i) {
    if (i < 0) i = -i;
    if (i > 223) i = 446 - i;
    return i;
}

static __device__ __forceinline__ void gauss_w(float* w) {
    float tot = 0.f;
#pragma unroll
    for (int j = 0; j < 17; ++j) {
        float t = (j - 8) * 0.25f;
        w[j] = expf(-0.5f * t * t);
        tot += w[j];
    }
    float inv = 1.f / tot;
#pragma unroll
    for (int j = 0; j < 17; ++j) w[j] *= inv;
}

__global__ __launch_bounds__(256)
void up_blurh_kernel(const unsigned* __restrict__ sb0, const unsigned* __restrict__ sb1,
                     const unsigned* __restrict__ sb2, float* __restrict__ tmp) {
    __shared__ float row[224];
    const int y = blockIdx.x, x = threadIdx.x;
    int y0, y1, x0, x1; float fy, fx;
    if (x < 224) {
        float v = 0.f;
        samp(y, 0.25f, 56, y0, y1, fy);   samp(x, 0.25f, 56, x0, x1, fx);
        v += bilerp_sq(sb0, 56, y0, y1, x0, x1, fy, fx);
        samp(y, 0.125f, 28, y0, y1, fy);  samp(x, 0.125f, 28, x0, x1, fx);
        v += bilerp_sq(sb1, 28, y0, y1, x0, x1, fy, fx);
        samp(y, 0.0625f, 14, y0, y1, fy); samp(x, 0.0625f, 14, x0, x1, fx);
        v += bilerp_sq(sb2, 14, y0, y1, x0, x1, fy, fx);
        row[x] = v;
    }
    __syncthreads();
    if (x < 224) {
        float w[17];
        gauss_w(w);
        float acc = 0.f;
#pragma unroll
        for (int j = 0; j < 17; ++j) acc += w[j] * row[reflect224(x + j - 8)];
        tmp[y * 224 + x] = acc;
    }
}

__global__ __launch_bounds__(256)
void blur_v_kernel(const float* __restrict__ in, float* __restrict__ out) {
    const int i = blockIdx.x * blockDim.x + threadIdx.x;
    if (i >= 224 * 224) return;
    const int y = i / 224, x = i % 224;
    float w[17];
    gauss_w(w);
    float acc = 0.f;
#pragma unroll
    for (int j = 0; j < 17; ++j) acc += w[j] * in[reflect224(y + j - 8) * 224 + x];
    out[i] = acc;
}

// ---------------------------------------------------------------------------
// Launch
// ---------------------------------------------------------------------------
extern "C" void kernel_launch(void* const* d_in, const int* in_sizes, int n_in,
                              void* d_out, int out_size, void* d_ws, size_t ws_size,
                              hipStream_t stream) {
    const float* z     = (const float*)d_in[0];
    const float* z_lib = (const float*)d_in[1];
    const float* fmap0 = (const float*)d_in[2];
    const float* fmap1 = (const float*)d_in[3];
    const float* fmap2 = (const float*)d_in[4];
    const float* lib0  = (const float*)d_in[5];
    const float* lib1  = (const float*)d_in[6];
    const float* lib2  = (const float*)d_in[7];
    const int*   kp    = (const int*)d_in[8];
    float* out = (float*)d_out;

    // workspace layout (16B aligned)
    constexpr size_t OFF_DIST2 = 0;                 // 128 f32
    constexpr size_t OFF_IDX   = 1024;              // 128 i32
    constexpr size_t OFF_SB0   = 2048;              // 3136 u32
    constexpr size_t OFF_SB1   = 2048 + 16384;      // 784 u32
    constexpr size_t OFF_SB2   = OFF_SB1 + 4096;    // 196 u32
    constexpr size_t OFF_TMP   = OFF_SB2 + 2048;    // 50176 f32
    constexpr size_t OFF_D2_0  = 262144;
    constexpr size_t SZ_D2_0   = (size_t)8  * NLIB * 784 * 16;
    constexpr size_t OFF_D2_1  = OFF_D2_0 + SZ_D2_0;
    constexpr size_t SZ_D2_1   = (size_t)16 * NLIB * 196 * 16;
    constexpr size_t OFF_D2_2  = OFF_D2_1 + SZ_D2_1;

    char* ws = (char*)d_ws;
    float*    dist2 = (float*)(ws + OFF_DIST2);
    int*      idx   = (int*)(ws + OFF_IDX);
    unsigned* sb0   = (unsigned*)(ws + OFF_SB0);
    unsigned* sb1   = (unsigned*)(ws + OFF_SB1);
    unsigned* sb2   = (unsigned*)(ws + OFF_SB2);
    float*    tmp   = (float*)(ws + OFF_TMP);
    float4*   d2_0  = (float4*)(ws + OFF_D2_0);
    float4*   d2_1  = (float4*)(ws + OFF_D2_1);
    float4*   d2_2  = (float4*)(ws + OFF_D2_2);

    // 1) per-row image distances
    row_dist_kernel<<<dim3(NLIB), dim3(256), 0, stream>>>(z, z_lib, dist2);
    // 2) rank-select + z_score + smin init
    select_kernel<<<dim3(1), dim3(128), 0, stream>>>(dist2, kp, out, idx, sb0, sb1, sb2);
    // 3) fused per-level distances (levels 0/1/2 in one grid)
    dist_all_kernel<<<dim3(51, NLIB), dim3(256), 0, stream>>>(
        lib0, fmap0, lib1, fmap1, lib2, fmap2, kp, idx, d2_0, d2_1, d2_2);
    // 4) min over k (atomicMin on uint bits)
    min_all_kernel<<<dim3(5, 16), dim3(256), 0, stream>>>(d2_0, d2_1, d2_2, kp, sb0, sb1, sb2);
    // 5) upsample + sum + blur-H (per-row)
    up_blurh_kernel<<<dim3(224), dim3(256), 0, stream>>>(sb0, sb1, sb2, tmp);
    // 6) blur-V
    blur_v_kernel<<<dim3(196), dim3(256), 0, stream>>>(tmp, out + 1);
}